// Round 13
// baseline (684.422 us; speedup 1.0000x reference)
//
#include <hip/hip_runtime.h>
#include <hip/hip_fp16.h>
#include <math.h>

#define NN 30000
#define NE 480000

typedef short bf16x8 __attribute__((ext_vector_type(8)));
typedef float f32x4 __attribute__((ext_vector_type(4)));

static __device__ __forceinline__ unsigned short f2b(float f) {
    union { float f; unsigned u; } v; v.f = f;
    unsigned r = v.u + 0x7FFF + ((v.u >> 16) & 1);
    return (unsigned short)(r >> 16);
}
static __device__ __forceinline__ float b2f(unsigned short s) {
    union { unsigned u; float f; } v; v.u = ((unsigned)s) << 16; return v.f;
}
static __device__ __forceinline__ unsigned short f2h(float f) {
    return __half_as_ushort(__float2half(f));
}
static __device__ __forceinline__ float2 uph2(unsigned u) {
    __half2 h = *(__half2*)&u;
    float2 r; r.x = __low2float(h); r.y = __high2float(h); return r;
}

// Bijective XCD-aware block swizzle (m204)
static __device__ __forceinline__ int xcd_swz(int bid, int nwg) {
    int q = nwg >> 3, r = nwg & 7;
    int xcd = bid & 7, idx = bid >> 3;
    int base = (xcd < r) ? xcd * (q + 1) : r * (q + 1) + (xcd - r) * q;
    return base + idx;
}

// Sum across the 16-lane DPP row; lane c==15 holds the full row sum.
static __device__ __forceinline__ float rowsum16(float v) {
    union { float f; int i; } u, t;
    u.f = v;
    t.i = __builtin_amdgcn_update_dpp(0, u.i, 0x111, 0xf, 0xf, true); u.f += t.f;
    t.i = __builtin_amdgcn_update_dpp(0, u.i, 0x112, 0xf, 0xf, true); u.f += t.f;
    t.i = __builtin_amdgcn_update_dpp(0, u.i, 0x114, 0xf, 0xf, true); u.f += t.f;
    t.i = __builtin_amdgcn_update_dpp(0, u.i, 0x118, 0xf, 0xf, true); u.f += t.f;
    return u.f;
}

// ---------------- CSR build (by dst) ----------------
__global__ void k_count(const int* __restrict__ dst, int* __restrict__ cnt) {
    int e = blockIdx.x * 256 + threadIdx.x;
    if (e < NE) atomicAdd(&cnt[dst[e]], 1);
}

__global__ __launch_bounds__(1024) void k_scanA(const int* __restrict__ cnt,
                                                int* __restrict__ off,
                                                int* __restrict__ bsum) {
    __shared__ int s[1024];
    int tid = threadIdx.x;
    int i = blockIdx.x * 1024 + tid;
    int v = (i < NN) ? cnt[i] : 0;
    s[tid] = v;
    __syncthreads();
    for (int d = 1; d < 1024; d <<= 1) {
        int t = (tid >= d) ? s[tid - d] : 0;
        __syncthreads();
        s[tid] += t;
        __syncthreads();
    }
    if (i < NN) off[i] = s[tid] - v;
    if (tid == 1023) bsum[blockIdx.x] = s[1023];
}

__global__ void k_scanB(const int* __restrict__ bsum, int* __restrict__ bbase, int nb) {
    if (threadIdx.x == 0) {
        int run = 0;
        for (int i = 0; i < nb; ++i) { bbase[i] = run; run += bsum[i]; }
    }
}

__global__ __launch_bounds__(1024) void k_scanC(int* __restrict__ off,
                                                int* __restrict__ cur,
                                                const int* __restrict__ bbase) {
    int i = blockIdx.x * 1024 + threadIdx.x;
    if (i < NN) {
        int o = off[i] + bbase[blockIdx.x];
        off[i] = o;
        cur[i] = o;
        if (i == 0) off[NN] = NE;
    }
}

__global__ void k_fill(const int* __restrict__ dst, int* __restrict__ cur,
                       int* __restrict__ eid) {
    int e = blockIdx.x * 256 + threadIdx.x;
    if (e < NE) {
        int p = atomicAdd(&cur[dst[e]], 1);
        eid[p] = e;
    }
}

// edge-GEMM weights (single bf16)
__global__ void k_convw(const float* __restrict__ We1, const float* __restrict__ We2,
                        unsigned short* __restrict__ W1b, unsigned short* __restrict__ W2b) {
    int i = blockIdx.x * 256 + threadIdx.x;
    if (i < 128 * 64) {
        int r = i >> 6, k = i & 63;
        W1b[i] = f2b(We1[(size_t)r * 192 + 64 + k]);
    } else if (i < 128 * 64 + 256 * 128) {
        int j = i - 128 * 64;
        int r = j >> 7, k = j & 127;
        W2b[j] = f2b(We2[(size_t)r * 384 + 128 + k]);
    }
}

// node-proj weights, split hi/lo bf16.
__global__ void k_convsplit(const float* __restrict__ Wn1, const float* __restrict__ We1,
                            const float* __restrict__ Wn2, const float* __restrict__ We2,
                            unsigned short* __restrict__ W1h, unsigned short* __restrict__ W1l,
                            unsigned short* __restrict__ W2h, unsigned short* __restrict__ W2l) {
    int i = blockIdx.x * 256 + threadIdx.x;
    if (i < 384 * 64) {
        int r = i >> 6, k = i & 63;
        float v;
        if (r < 128)      v = Wn1[(size_t)r * 64 + k];
        else if (r < 256) v = We1[(size_t)(r - 128) * 192 + k];
        else              v = We1[(size_t)(r - 256) * 192 + 128 + k];
        unsigned short h = f2b(v);
        W1h[i] = h; W1l[i] = f2b(v - b2f(h));
    } else if (i < 384 * 64 + 768 * 128) {
        int j = i - 384 * 64;
        int r = j >> 7, k = j & 127;
        float v;
        if (r < 256)      v = Wn2[(size_t)r * 128 + k];
        else if (r < 512) v = We2[(size_t)(r - 256) * 384 + k];
        else              v = We2[(size_t)(r - 512) * 384 + 256 + k];
        unsigned short h = f2b(v);
        W2h[j] = h; W2l[j] = f2b(v - b2f(h));
    }
}

// ---------------- fused: permute edges + convert ef to bf16 + per-node sum ----------------
__global__ void k_permagg(const float* __restrict__ ef, const int* __restrict__ eid,
                          const int* __restrict__ src, const int* __restrict__ dst,
                          const int* __restrict__ off,
                          unsigned short* __restrict__ efb_p, int* __restrict__ src_p,
                          int* __restrict__ dst_p,
                          unsigned short* __restrict__ hn1h, unsigned short* __restrict__ hn1l) {
    int bid = xcd_swz(blockIdx.x, gridDim.x);
    int w = bid * 4 + (threadIdx.x >> 6);
    int lane = threadIdx.x & 63;
    if (w >= NN) return;
    int s0 = off[w], s1 = off[w + 1];
    float acc = 0.f;
    int i = s0;
    for (; i + 4 <= s1; i += 4) {
        int e0 = eid[i], e1 = eid[i + 1], e2 = eid[i + 2], e3 = eid[i + 3];
        float v0 = ef[(size_t)e0 * 64 + lane];
        float v1 = ef[(size_t)e1 * 64 + lane];
        float v2 = ef[(size_t)e2 * 64 + lane];
        float v3 = ef[(size_t)e3 * 64 + lane];
        if (lane == 0) {
            src_p[i] = src[e0]; dst_p[i] = dst[e0];
            src_p[i + 1] = src[e1]; dst_p[i + 1] = dst[e1];
            src_p[i + 2] = src[e2]; dst_p[i + 2] = dst[e2];
            src_p[i + 3] = src[e3]; dst_p[i + 3] = dst[e3];
        }
        efb_p[(size_t)i * 64 + lane] = f2b(v0);
        efb_p[(size_t)(i + 1) * 64 + lane] = f2b(v1);
        efb_p[(size_t)(i + 2) * 64 + lane] = f2b(v2);
        efb_p[(size_t)(i + 3) * 64 + lane] = f2b(v3);
        acc += v0; acc += v1; acc += v2; acc += v3;
    }
    for (; i < s1; ++i) {
        int e = eid[i];
        float v = ef[(size_t)e * 64 + lane];
        if (lane == 0) { src_p[i] = src[e]; dst_p[i] = dst[e]; }
        efb_p[(size_t)i * 64 + lane] = f2b(v);
        acc += v;
    }
    unsigned short h = f2b(acc);
    hn1h[(size_t)w * 64 + lane] = h;
    hn1l[(size_t)w * 64 + lane] = f2b(acc - b2f(h));
}

// ---------------- fp16 table store helpers ----------------
static __device__ __forceinline__ void store_p1(unsigned short* hp1, unsigned short* pa1,
                                                unsigned short* pc1, int n, int o, float v) {
    unsigned short h = f2h(v);
    if (o < 128) {
        hp1[(size_t)n * 128 + (o & 63) * 2 + (o >> 6)] = h;
    } else if (o < 256) {
        int x = o - 128;
        pa1[(size_t)n * 128 + ((x >> 5) * 16 + (x & 15)) * 2 + ((x >> 4) & 1)] = h;
    } else {
        int x = o - 256;
        pc1[(size_t)n * 128 + ((x >> 5) * 16 + (x & 15)) * 2 + ((x >> 4) & 1)] = h;
    }
}

static __device__ __forceinline__ void store_p2(unsigned short* hp2, unsigned short* pa2,
                                                unsigned short* pc2, int n, int o, float v) {
    unsigned short h = f2h(v);
    if (o < 256) {
        hp2[(size_t)n * 256 + (o & 63) * 4 + (o >> 6)] = h;
    } else if (o < 512) {
        int x = o - 256;
        pa2[(size_t)n * 256 + (x & 63) * 4 + (x >> 6)] = h;
    } else {
        int x = o - 512;
        pc2[(size_t)n * 256 + (x & 63) * 4 + (x >> 6)] = h;
    }
}

// ---------------- node projections layer1 (split-bf16 MFMA, no LDS) ----------------
__global__ __launch_bounds__(256) void k_nodeproj1(
        const unsigned short* __restrict__ hn1h, const unsigned short* __restrict__ hn1l,
        const unsigned short* __restrict__ W1h, const unsigned short* __restrict__ W1l,
        const float* __restrict__ b1,
        unsigned short* __restrict__ hp1, unsigned short* __restrict__ pa1,
        unsigned short* __restrict__ pc1) {
    int tid = threadIdx.x;
    int w = tid >> 6, l = tid & 63;
    int c = l & 15, g = l >> 4;
    int pb = blockIdx.x * 16;

    f32x4 acc[6];
#pragma unroll
    for (int t = 0; t < 6; ++t) acc[t] = (f32x4)(0.f);

#pragma unroll
    for (int kk = 0; kk < 2; ++kk) {
        int arow = pb + c;
        bf16x8 ah = *(const bf16x8*)&hn1h[(size_t)arow * 64 + kk * 32 + g * 8];
        bf16x8 al = *(const bf16x8*)&hn1l[(size_t)arow * 64 + kk * 32 + g * 8];
#pragma unroll
        for (int t = 0; t < 6; ++t) {
            int brow = w * 96 + t * 16 + c;
            bf16x8 bh = *(const bf16x8*)&W1h[(size_t)brow * 64 + kk * 32 + g * 8];
            bf16x8 bl = *(const bf16x8*)&W1l[(size_t)brow * 64 + kk * 32 + g * 8];
            acc[t] = __builtin_amdgcn_mfma_f32_16x16x32_bf16(ah, bh, acc[t], 0, 0, 0);
            acc[t] = __builtin_amdgcn_mfma_f32_16x16x32_bf16(ah, bl, acc[t], 0, 0, 0);
            acc[t] = __builtin_amdgcn_mfma_f32_16x16x32_bf16(al, bh, acc[t], 0, 0, 0);
        }
    }

#pragma unroll
    for (int t = 0; t < 6; ++t) {
        int og = w * 96 + t * 16 + c;
        float bias = (og < 128) ? b1[og] : 0.f;
#pragma unroll
        for (int r = 0; r < 4; ++r) {
            int n = pb + g * 4 + r;
            if (n < NN) store_p1(hp1, pa1, pc1, n, og, acc[t][r] + bias);
        }
    }
}

// ---------------- edge GEMM layer1 (gathers hoisted above MFMA) ----------------
__global__ __launch_bounds__(256) void k_gemm1(
        const unsigned short* __restrict__ efb_p, const int* __restrict__ src_p,
        const int* __restrict__ dst_p, const unsigned short* __restrict__ W1b,
        const float* __restrict__ Wa1, const unsigned short* __restrict__ pa1,
        const unsigned short* __restrict__ pc1,
        unsigned short* __restrict__ he1b, float* __restrict__ a1) {
    int tid = threadIdx.x;
    int w = tid >> 6, l = tid & 63;
    int c = l & 15, g = l >> 4;
    int pb = blockIdx.x * 64;

    const unsigned* paH = (const unsigned*)pa1;
    const unsigned* pcH = (const unsigned*)pc1;

    // 1) indices + issue ALL gathers first
    int ss[16], dd[16];
#pragma unroll
    for (int m = 0; m < 4; ++m) {
        int4 s4 = *(const int4*)&src_p[pb + m * 16 + g * 4];
        int4 d4 = *(const int4*)&dst_p[pb + m * 16 + g * 4];
        ss[m * 4 + 0] = s4.x; ss[m * 4 + 1] = s4.y; ss[m * 4 + 2] = s4.z; ss[m * 4 + 3] = s4.w;
        dd[m * 4 + 0] = d4.x; dd[m * 4 + 1] = d4.y; dd[m * 4 + 2] = d4.z; dd[m * 4 + 3] = d4.w;
    }
    unsigned ua[16], uc[16];
#pragma unroll
    for (int mm = 0; mm < 16; ++mm) {
        ua[mm] = paH[(size_t)ss[mm] * 64 + w * 16 + c];
        uc[mm] = pcH[(size_t)dd[mm] * 64 + w * 16 + c];
    }

    // 2) MFMA phase (gather latency hides under this)
    f32x4 acc[4][2];
    for (int m = 0; m < 4; ++m)
        for (int t = 0; t < 2; ++t) acc[m][t] = (f32x4)(0.f);

#pragma unroll
    for (int kk = 0; kk < 2; ++kk) {
        bf16x8 b[2];
#pragma unroll
        for (int t = 0; t < 2; ++t)
            b[t] = *(const bf16x8*)&W1b[(size_t)((2 * w + t) * 16 + c) * 64 + kk * 32 + g * 8];
#pragma unroll
        for (int m = 0; m < 4; ++m) {
            bf16x8 a = *(const bf16x8*)&efb_p[(size_t)(pb + m * 16 + c) * 64 + kk * 32 + g * 8];
#pragma unroll
            for (int t = 0; t < 2; ++t)
                acc[m][t] = __builtin_amdgcn_mfma_f32_16x16x32_bf16(a, b[t], acc[m][t], 0, 0, 0);
        }
    }

    float wsj0 = Wa1[c] + Wa1[32 + c] + Wa1[64 + c] + Wa1[96 + c];
    float wsj1 = Wa1[16 + c] + Wa1[48 + c] + Wa1[80 + c] + Wa1[112 + c];

    // 3) epilogue
#pragma unroll
    for (int m = 0; m < 4; ++m) {
#pragma unroll
        for (int r = 0; r < 4; ++r) {
            int pos = pb + m * 16 + g * 4 + r;
            float2 av2 = uph2(ua[m * 4 + r]);
            float2 cv2 = uph2(uc[m * 4 + r]);
            float f0 = acc[m][0][r] + av2.x + cv2.x;
            float f1 = acc[m][1][r] + av2.y + cv2.y;
            float lf0 = (f0 > 0.f) ? f0 : 0.01f * f0;
            float lf1 = (f1 > 0.f) ? f1 : 0.01f * f1;
            float av = lf0 * wsj0 + lf1 * wsj1;
            he1b[(size_t)pos * 128 + w * 32 + c]      = f2b((lf0 > 0.f) ? lf0 : expm1f(lf0));
            he1b[(size_t)pos * 128 + w * 32 + 16 + c] = f2b((lf1 > 0.f) ? lf1 : expm1f(lf1));
            av = rowsum16(av);
            if (c == 15) a1[(size_t)pos * 4 + w] = av;
        }
    }
}

// ---------------- segment softmax + weighted aggregate, layer1 -> hi/lo bf16 ----------------
__global__ void k_agg1(const float* __restrict__ a1, const int* __restrict__ off,
                       const int* __restrict__ src_p, const unsigned short* __restrict__ hp1,
                       unsigned short* __restrict__ hn1oh, unsigned short* __restrict__ hn1ol) {
    __shared__ float4 alf[4][64];
    int wv = threadIdx.x >> 6;
    int w = xcd_swz(blockIdx.x, gridDim.x) * 4 + wv;
    int lane = threadIdx.x & 63;
    if (w >= NN) return;
    int s0 = off[w], s1 = off[w + 1];
    if (s1 == s0) {
        hn1oh[(size_t)w * 128 + lane] = 0; hn1oh[(size_t)w * 128 + 64 + lane] = 0;
        hn1ol[(size_t)w * 128 + lane] = 0; hn1ol[(size_t)w * 128 + 64 + lane] = 0;
        return;
    }
    float m[4] = {-INFINITY, -INFINITY, -INFINITY, -INFINITY};
    for (int i = s0 + lane; i < s1; i += 64) {
        float4 av = *(const float4*)&a1[(size_t)i * 4];
        m[0] = fmaxf(m[0], av.x); m[1] = fmaxf(m[1], av.y);
        m[2] = fmaxf(m[2], av.z); m[3] = fmaxf(m[3], av.w);
    }
#pragma unroll
    for (int d = 1; d < 64; d <<= 1) {
        m[0] = fmaxf(m[0], __shfl_xor(m[0], d, 64));
        m[1] = fmaxf(m[1], __shfl_xor(m[1], d, 64));
        m[2] = fmaxf(m[2], __shfl_xor(m[2], d, 64));
        m[3] = fmaxf(m[3], __shfl_xor(m[3], d, 64));
    }
    float den[4] = {0.f, 0.f, 0.f, 0.f};
    for (int i = s0 + lane; i < s1; i += 64) {
        float4 av = *(const float4*)&a1[(size_t)i * 4];
        den[0] += expf(av.x - m[0]); den[1] += expf(av.y - m[1]);
        den[2] += expf(av.z - m[2]); den[3] += expf(av.w - m[3]);
    }
#pragma unroll
    for (int d = 1; d < 64; d <<= 1) {
        den[0] += __shfl_xor(den[0], d, 64);
        den[1] += __shfl_xor(den[1], d, 64);
        den[2] += __shfl_xor(den[2], d, 64);
        den[3] += __shfl_xor(den[3], d, 64);
    }
    float r0 = 1.f / den[0], r1 = 1.f / den[1], r2 = 1.f / den[2], r3 = 1.f / den[3];
    int h0 = lane >> 5;
    const unsigned* hpH = (const unsigned*)hp1;
    float acc0 = 0.f, acc1 = 0.f;
    for (int base = s0; base < s1; base += 64) {
        int i = base + lane;
        if (i < s1) {
            float4 av = *(const float4*)&a1[(size_t)i * 4];
            float4 al;
            al.x = expf(av.x - m[0]) * r0;
            al.y = expf(av.y - m[1]) * r1;
            al.z = expf(av.z - m[2]) * r2;
            al.w = expf(av.w - m[3]) * r3;
            alf[wv][lane] = al;
        }
        int lim = s1 - base; if (lim > 64) lim = 64;
        int k = 0;
        for (; k + 8 <= lim; k += 8) {
            int sx[8];
            unsigned ux[8];
#pragma unroll
            for (int q = 0; q < 8; ++q) sx[q] = src_p[base + k + q];
#pragma unroll
            for (int q = 0; q < 8; ++q) ux[q] = hpH[(size_t)sx[q] * 64 + lane];
#pragma unroll
            for (int q = 0; q < 8; ++q) {
                float4 aq = alf[wv][k + q];
                float2 u = uph2(ux[q]);
                float w0 = (h0 == 0) ? aq.x : aq.y;
                float w1 = (h0 == 0) ? aq.z : aq.w;
                acc0 += w0 * u.x;
                acc1 += w1 * u.y;
            }
        }
        for (; k < lim; ++k) {
            float4 al = alf[wv][k];
            int s = src_p[base + k];
            float2 u = uph2(hpH[(size_t)s * 64 + lane]);
            float w0 = (h0 == 0) ? al.x : al.y;
            float w1 = (h0 == 0) ? al.z : al.w;
            acc0 += w0 * u.x;
            acc1 += w1 * u.y;
        }
    }
    float e0 = (acc0 > 0.f) ? acc0 : expm1f(acc0);
    float e1 = (acc1 > 0.f) ? acc1 : expm1f(acc1);
    unsigned short h0s = f2b(e0), h1s = f2b(e1);
    hn1oh[(size_t)w * 128 + lane] = h0s;
    hn1ol[(size_t)w * 128 + lane] = f2b(e0 - b2f(h0s));
    hn1oh[(size_t)w * 128 + 64 + lane] = h1s;
    hn1ol[(size_t)w * 128 + 64 + lane] = f2b(e1 - b2f(h1s));
}

// ---------------- node projections layer2 (split-bf16 MFMA, no LDS) ----------------
__global__ __launch_bounds__(256) void k_nodeproj2(
        const unsigned short* __restrict__ hn1oh, const unsigned short* __restrict__ hn1ol,
        const unsigned short* __restrict__ W2h, const unsigned short* __restrict__ W2l,
        const float* __restrict__ b2,
        unsigned short* __restrict__ hp2, unsigned short* __restrict__ pa2,
        unsigned short* __restrict__ pc2) {
    int tid = threadIdx.x;
    int w = tid >> 6, l = tid & 63;
    int c = l & 15, g = l >> 4;
    int pb = blockIdx.x * 16;

    f32x4 acc[12];
#pragma unroll
    for (int t = 0; t < 12; ++t) acc[t] = (f32x4)(0.f);

#pragma unroll
    for (int kk = 0; kk < 4; ++kk) {
        int arow = pb + c;
        bf16x8 ah = *(const bf16x8*)&hn1oh[(size_t)arow * 128 + kk * 32 + g * 8];
        bf16x8 al = *(const bf16x8*)&hn1ol[(size_t)arow * 128 + kk * 32 + g * 8];
#pragma unroll
        for (int t = 0; t < 12; ++t) {
            int brow = w * 192 + t * 16 + c;
            bf16x8 bh = *(const bf16x8*)&W2h[(size_t)brow * 128 + kk * 32 + g * 8];
            bf16x8 bl = *(const bf16x8*)&W2l[(size_t)brow * 128 + kk * 32 + g * 8];
            acc[t] = __builtin_amdgcn_mfma_f32_16x16x32_bf16(ah, bh, acc[t], 0, 0, 0);
            acc[t] = __builtin_amdgcn_mfma_f32_16x16x32_bf16(ah, bl, acc[t], 0, 0, 0);
            acc[t] = __builtin_amdgcn_mfma_f32_16x16x32_bf16(al, bh, acc[t], 0, 0, 0);
        }
    }

#pragma unroll
    for (int t = 0; t < 12; ++t) {
        int og = w * 192 + t * 16 + c;
        float bias = (og < 256) ? b2[og] : 0.f;
#pragma unroll
        for (int r = 0; r < 4; ++r) {
            int n = pb + g * 4 + r;
            if (n < NN) store_p2(hp2, pa2, pc2, n, og, acc[t][r] + bias);
        }
    }
}

// ---------------- edge GEMM layer2 (gathers hoisted above MFMA): a2 + heo ----------------
__global__ __launch_bounds__(256) void k_gemm2(
        const unsigned short* __restrict__ he1b, const int* __restrict__ src_p,
        const int* __restrict__ dst_p, const int* __restrict__ eid,
        const unsigned short* __restrict__ W2b, const float* __restrict__ Wa2,
        const unsigned short* __restrict__ pa2, const unsigned short* __restrict__ pc2,
        float* __restrict__ heo, float* __restrict__ a2) {
    __shared__ float a2l[4 * 64 * 4];
    int tid = threadIdx.x;
    int w = tid >> 6, l = tid & 63;
    int c = l & 15, g = l >> 4;
    int j = w * 16 + c;
    int pb = blockIdx.x * 64;

    const uint2* paH = (const uint2*)pa2;
    const uint2* pcH = (const uint2*)pc2;

    // 1) indices + issue ALL gathers first
    int ss[16], dd[16];
#pragma unroll
    for (int m = 0; m < 4; ++m) {
        int4 s4 = *(const int4*)&src_p[pb + m * 16 + g * 4];
        int4 d4 = *(const int4*)&dst_p[pb + m * 16 + g * 4];
        ss[m * 4 + 0] = s4.x; ss[m * 4 + 1] = s4.y; ss[m * 4 + 2] = s4.z; ss[m * 4 + 3] = s4.w;
        dd[m * 4 + 0] = d4.x; dd[m * 4 + 1] = d4.y; dd[m * 4 + 2] = d4.z; dd[m * 4 + 3] = d4.w;
    }
    uint2 ua[16], uc[16];
#pragma unroll
    for (int mm = 0; mm < 16; ++mm) {
        ua[mm] = paH[(size_t)ss[mm] * 64 + j];
        uc[mm] = pcH[(size_t)dd[mm] * 64 + j];
    }

    // 2) MFMA phase (gather latency hides under this)
    f32x4 acc[4][4];
    for (int m = 0; m < 4; ++m)
        for (int t = 0; t < 4; ++t) acc[m][t] = (f32x4)(0.f);

#pragma unroll
    for (int kk = 0; kk < 4; ++kk) {
        bf16x8 b[4];
#pragma unroll
        for (int t = 0; t < 4; ++t)
            b[t] = *(const bf16x8*)&W2b[(size_t)((w + 4 * t) * 16 + c) * 128 + kk * 32 + g * 8];
#pragma unroll
        for (int m = 0; m < 4; ++m) {
            bf16x8 a = *(const bf16x8*)&he1b[(size_t)(pb + m * 16 + c) * 128 + kk * 32 + g * 8];
#pragma unroll
            for (int t = 0; t < 4; ++t)
                acc[m][t] = __builtin_amdgcn_mfma_f32_16x16x32_bf16(a, b[t], acc[m][t], 0, 0, 0);
        }
    }

    float wsj = Wa2[j] + Wa2[64 + j] + Wa2[128 + j] + Wa2[192 + j];

    // 3) epilogue
#pragma unroll
    for (int m = 0; m < 4; ++m) {
        int4 e4 = *(const int4*)&eid[pb + m * 16 + g * 4];
        int ee[4] = {e4.x, e4.y, e4.z, e4.w};
#pragma unroll
        for (int r = 0; r < 4; ++r) {
            int le = m * 16 + g * 4 + r;
            float2 a01 = uph2(ua[m * 4 + r].x), a23 = uph2(ua[m * 4 + r].y);
            float2 c01 = uph2(uc[m * 4 + r].x), c23 = uph2(uc[m * 4 + r].y);
            float f[4];
            f[0] = acc[m][0][r] + a01.x + c01.x;
            f[1] = acc[m][1][r] + a01.y + c01.y;
            f[2] = acc[m][2][r] + a23.x + c23.x;
            f[3] = acc[m][3][r] + a23.y + c23.y;
            float hsum = 0.f;
            float avt[4];
#pragma unroll
            for (int t = 0; t < 4; ++t) {
                float lf = (f[t] > 0.f) ? f[t] : 0.01f * f[t];
                hsum += lf;
                avt[t] = lf * wsj;
            }
#pragma unroll
            for (int t = 0; t < 4; ++t) avt[t] = rowsum16(avt[t]);
            if (c == 15) {
                float4 st = make_float4(avt[0], avt[1], avt[2], avt[3]);
                *(float4*)&a2l[(w * 64 + le) * 4] = st;
            }
            heo[(size_t)ee[r] * 64 + j] = 0.25f * hsum;
        }
    }
    __syncthreads();
    {
        int pos = tid >> 2, t = tid & 3;
        float v = a2l[(0 * 64 + pos) * 4 + t] + a2l[(1 * 64 + pos) * 4 + t]
                + a2l[(2 * 64 + pos) * 4 + t] + a2l[(3 * 64 + pos) * 4 + t];
        a2[(size_t)(pb + pos) * 4 + t] = v;
    }
}

// ---------------- segment softmax + aggregate + head-mean, layer2 ----------------
__global__ void k_agg2(const float* __restrict__ a2, const int* __restrict__ off,
                       const int* __restrict__ src_p, const unsigned short* __restrict__ hp2,
                       float* __restrict__ hno) {
    __shared__ float4 alf[4][64];
    int wv = threadIdx.x >> 6;
    int w = xcd_swz(blockIdx.x, gridDim.x) * 4 + wv;
    int lane = threadIdx.x & 63;
    if (w >= NN) return;
    int s0 = off[w], s1 = off[w + 1];
    if (s1 == s0) {
        hno[(size_t)w * 64 + lane] = 0.f;
        return;
    }
    float m[4] = {-INFINITY, -INFINITY, -INFINITY, -INFINITY};
    for (int i = s0 + lane; i < s1; i += 64) {
        float4 av = *(const float4*)&a2[(size_t)i * 4];
        m[0] = fmaxf(m[0], av.x); m[1] = fmaxf(m[1], av.y);
        m[2] = fmaxf(m[2], av.z); m[3] = fmaxf(m[3], av.w);
    }
#pragma unroll
    for (int d = 1; d < 64; d <<= 1) {
        m[0] = fmaxf(m[0], __shfl_xor(m[0], d, 64));
        m[1] = fmaxf(m[1], __shfl_xor(m[1], d, 64));
        m[2] = fmaxf(m[2], __shfl_xor(m[2], d, 64));
        m[3] = fmaxf(m[3], __shfl_xor(m[3], d, 64));
    }
    float den[4] = {0.f, 0.f, 0.f, 0.f};
    for (int i = s0 + lane; i < s1; i += 64) {
        float4 av = *(const float4*)&a2[(size_t)i * 4];
        den[0] += expf(av.x - m[0]); den[1] += expf(av.y - m[1]);
        den[2] += expf(av.z - m[2]); den[3] += expf(av.w - m[3]);
    }
#pragma unroll
    for (int d = 1; d < 64; d <<= 1) {
        den[0] += __shfl_xor(den[0], d, 64);
        den[1] += __shfl_xor(den[1], d, 64);
        den[2] += __shfl_xor(den[2], d, 64);
        den[3] += __shfl_xor(den[3], d, 64);
    }
    float r0 = 1.f / den[0], r1 = 1.f / den[1], r2 = 1.f / den[2], r3 = 1.f / den[3];
    const uint2* hpH = (const uint2*)hp2;
    float acc0 = 0.f, acc1 = 0.f, acc2 = 0.f, acc3 = 0.f;
    for (int base = s0; base < s1; base += 64) {
        int i = base + lane;
        if (i < s1) {
            float4 av = *(const float4*)&a2[(size_t)i * 4];
            float4 al;
            al.x = expf(av.x - m[0]) * r0;
            al.y = expf(av.y - m[1]) * r1;
            al.z = expf(av.z - m[2]) * r2;
            al.w = expf(av.w - m[3]) * r3;
            alf[wv][lane] = al;
        }
        int lim = s1 - base; if (lim > 64) lim = 64;
        int k = 0;
        for (; k + 8 <= lim; k += 8) {
            int sx[8];
            uint2 ux[8];
#pragma unroll
            for (int q = 0; q < 8; ++q) sx[q] = src_p[base + k + q];
#pragma unroll
            for (int q = 0; q < 8; ++q) ux[q] = hpH[(size_t)sx[q] * 64 + lane];
#pragma unroll
            for (int q = 0; q < 8; ++q) {
                float4 aq = alf[wv][k + q];
                float2 u01 = uph2(ux[q].x), u23 = uph2(ux[q].y);
                acc0 += aq.x * u01.x;
                acc1 += aq.y * u01.y;
                acc2 += aq.z * u23.x;
                acc3 += aq.w * u23.y;
            }
        }
        for (; k < lim; ++k) {
            float4 al = alf[wv][k];
            int s = src_p[base + k];
            uint2 u = hpH[(size_t)s * 64 + lane];
            float2 u01 = uph2(u.x), u23 = uph2(u.y);
            acc0 += al.x * u01.x;
            acc1 += al.y * u01.y;
            acc2 += al.z * u23.x;
            acc3 += al.w * u23.y;
        }
    }
    hno[(size_t)w * 64 + lane] = 0.25f * (acc0 + acc1 + acc2 + acc3);
}

extern "C" void kernel_launch(void* const* d_in, const int* in_sizes, int n_in,
                              void* d_out, int out_size, void* d_ws, size_t ws_size,
                              hipStream_t stream) {
    const float* efeats = (const float*)d_in[1];
    const int* src = (const int*)d_in[2];
    const int* dst = (const int*)d_in[3];
    const float* Wn1 = (const float*)d_in[4];
    const float* b1  = (const float*)d_in[5];
    const float* We1 = (const float*)d_in[6];
    const float* Wa1 = (const float*)d_in[7];
    const float* Wn2 = (const float*)d_in[8];
    const float* b2  = (const float*)d_in[9];
    const float* We2 = (const float*)d_in[10];
    const float* Wa2 = (const float*)d_in[11];

    const int NNP = 30016;

    char* ws = (char*)d_ws;
    size_t o = 0;
    auto alloc = [&](size_t bytes) {
        void* p = ws + o;
        o += (bytes + 255) & ~(size_t)255;
        return p;
    };
    int* cnt   = (int*)alloc((size_t)NN * 4);
    int* off   = (int*)alloc((size_t)(NN + 1) * 4);
    int* cur   = (int*)alloc((size_t)NN * 4);
    int* eid   = (int*)alloc((size_t)NE * 4);
    int* src_p = (int*)alloc((size_t)NE * 4);
    int* dst_p = (int*)alloc((size_t)NE * 4);
    int* bsum  = (int*)alloc(64 * 4);
    int* bbase = (int*)alloc(64 * 4);
    float* a1  = (float*)alloc((size_t)NE * 4 * 4);   // reused as a2
    unsigned short* efb_p = (unsigned short*)alloc((size_t)NE * 64 * 2);
    unsigned short* he1b  = (unsigned short*)alloc((size_t)NE * 128 * 2);
    unsigned short* W1b   = (unsigned short*)alloc((size_t)128 * 64 * 2);
    unsigned short* W2b   = (unsigned short*)alloc((size_t)256 * 128 * 2);
    unsigned short* W1h   = (unsigned short*)alloc((size_t)384 * 64 * 2);
    unsigned short* W1l   = (unsigned short*)alloc((size_t)384 * 64 * 2);
    unsigned short* W2h   = (unsigned short*)alloc((size_t)768 * 128 * 2);
    unsigned short* W2l   = (unsigned short*)alloc((size_t)768 * 128 * 2);
    unsigned short* hn1h  = (unsigned short*)alloc((size_t)NNP * 64 * 2);
    unsigned short* hn1l  = (unsigned short*)alloc((size_t)NNP * 64 * 2);
    unsigned short* hn1oh = (unsigned short*)alloc((size_t)NNP * 128 * 2);
    unsigned short* hn1ol = (unsigned short*)alloc((size_t)NNP * 128 * 2);
    unsigned short* hp1   = (unsigned short*)alloc((size_t)NN * 128 * 2);
    unsigned short* pa1   = (unsigned short*)alloc((size_t)NN * 128 * 2);
    unsigned short* pc1   = (unsigned short*)alloc((size_t)NN * 128 * 2);
    unsigned short* hp2   = (unsigned short*)alloc((size_t)NN * 256 * 2);
    unsigned short* pa2   = (unsigned short*)alloc((size_t)NN * 256 * 2);
    unsigned short* pc2   = (unsigned short*)alloc((size_t)NN * 256 * 2);

    float* hno = (float*)d_out;
    float* heo = (float*)d_out + (size_t)NN * 64;

    const int SCAN_B = (NN + 1023) / 1024;
    const int NPB = NNP / 16;
    hipMemsetAsync(cnt, 0, (size_t)NN * 4, stream);
    k_count<<<(NE + 255) / 256, 256, 0, stream>>>(dst, cnt);
    k_scanA<<<SCAN_B, 1024, 0, stream>>>(cnt, off, bsum);
    k_scanB<<<1, 64, 0, stream>>>(bsum, bbase, SCAN_B);
    k_scanC<<<SCAN_B, 1024, 0, stream>>>(off, cur, bbase);
    k_fill<<<(NE + 255) / 256, 256, 0, stream>>>(dst, cur, eid);
    k_convw<<<(128 * 64 + 256 * 128 + 255) / 256, 256, 0, stream>>>(We1, We2, W1b, W2b);
    k_convsplit<<<(384 * 64 + 768 * 128 + 255) / 256, 256, 0, stream>>>(
        Wn1, We1, Wn2, We2, W1h, W1l, W2h, W2l);
    k_permagg<<<NN / 4, 256, 0, stream>>>(efeats, eid, src, dst, off, efb_p, src_p, dst_p,
                                          hn1h, hn1l);
    k_nodeproj1<<<NPB, 256, 0, stream>>>(hn1h, hn1l, W1h, W1l, b1, hp1, pa1, pc1);
    k_gemm1<<<NE / 64, 256, 0, stream>>>(efb_p, src_p, dst_p, W1b, Wa1, pa1, pc1, he1b, a1);
    k_agg1<<<NN / 4, 256, 0, stream>>>(a1, off, src_p, hp1, hn1oh, hn1ol);
    k_nodeproj2<<<NPB, 256, 0, stream>>>(hn1oh, hn1ol, W2h, W2l, b2, hp2, pa2, pc2);
    k_gemm2<<<NE / 64, 256, 0, stream>>>(he1b, src_p, dst_p, eid, W2b, Wa2, pa2, pc2, heo, a1);
    k_agg2<<<NN / 4, 256, 0, stream>>>(a1, off, src_p, hp2, hno);
}

// Round 14
// 665.748 us; speedup vs baseline: 1.0280x; 1.0280x over previous
//
#include <hip/hip_runtime.h>
#include <hip/hip_fp16.h>
#include <math.h>

#define NN 30000
#define NE 480000

typedef short bf16x8 __attribute__((ext_vector_type(8)));
typedef float f32x4 __attribute__((ext_vector_type(4)));

static __device__ __forceinline__ unsigned short f2b(float f) {
    union { float f; unsigned u; } v; v.f = f;
    unsigned r = v.u + 0x7FFF + ((v.u >> 16) & 1);
    return (unsigned short)(r >> 16);
}
static __device__ __forceinline__ float b2f(unsigned short s) {
    union { unsigned u; float f; } v; v.u = ((unsigned)s) << 16; return v.f;
}
static __device__ __forceinline__ unsigned short f2h(float f) {
    return __half_as_ushort(__float2half(f));
}
static __device__ __forceinline__ float2 uph2(unsigned u) {
    __half2 h = *(__half2*)&u;
    float2 r; r.x = __low2float(h); r.y = __high2float(h); return r;
}

// Bijective XCD-aware block swizzle (m204)
static __device__ __forceinline__ int xcd_swz(int bid, int nwg) {
    int q = nwg >> 3, r = nwg & 7;
    int xcd = bid & 7, idx = bid >> 3;
    int base = (xcd < r) ? xcd * (q + 1) : r * (q + 1) + (xcd - r) * q;
    return base + idx;
}

// Sum across the 16-lane DPP row; lane c==15 holds the full row sum.
static __device__ __forceinline__ float rowsum16(float v) {
    union { float f; int i; } u, t;
    u.f = v;
    t.i = __builtin_amdgcn_update_dpp(0, u.i, 0x111, 0xf, 0xf, true); u.f += t.f;
    t.i = __builtin_amdgcn_update_dpp(0, u.i, 0x112, 0xf, 0xf, true); u.f += t.f;
    t.i = __builtin_amdgcn_update_dpp(0, u.i, 0x114, 0xf, 0xf, true); u.f += t.f;
    t.i = __builtin_amdgcn_update_dpp(0, u.i, 0x118, 0xf, 0xf, true); u.f += t.f;
    return u.f;
}

// ---------------- CSR build (by dst) ----------------
__global__ void k_count(const int* __restrict__ dst, int* __restrict__ cnt) {
    int e = blockIdx.x * 256 + threadIdx.x;
    if (e < NE) atomicAdd(&cnt[dst[e]], 1);
}

__global__ __launch_bounds__(1024) void k_scanA(const int* __restrict__ cnt,
                                                int* __restrict__ off,
                                                int* __restrict__ bsum) {
    __shared__ int s[1024];
    int tid = threadIdx.x;
    int i = blockIdx.x * 1024 + tid;
    int v = (i < NN) ? cnt[i] : 0;
    s[tid] = v;
    __syncthreads();
    for (int d = 1; d < 1024; d <<= 1) {
        int t = (tid >= d) ? s[tid - d] : 0;
        __syncthreads();
        s[tid] += t;
        __syncthreads();
    }
    if (i < NN) off[i] = s[tid] - v;
    if (tid == 1023) bsum[blockIdx.x] = s[1023];
}

__global__ void k_scanB(const int* __restrict__ bsum, int* __restrict__ bbase, int nb) {
    if (threadIdx.x == 0) {
        int run = 0;
        for (int i = 0; i < nb; ++i) { bbase[i] = run; run += bsum[i]; }
    }
}

__global__ __launch_bounds__(1024) void k_scanC(int* __restrict__ off,
                                                int* __restrict__ cur,
                                                const int* __restrict__ bbase) {
    int i = blockIdx.x * 1024 + threadIdx.x;
    if (i < NN) {
        int o = off[i] + bbase[blockIdx.x];
        off[i] = o;
        cur[i] = o;
        if (i == 0) off[NN] = NE;
    }
}

__global__ void k_fill(const int* __restrict__ dst, int* __restrict__ cur,
                       int* __restrict__ eid) {
    int e = blockIdx.x * 256 + threadIdx.x;
    if (e < NE) {
        int p = atomicAdd(&cur[dst[e]], 1);
        eid[p] = e;
    }
}

// edge-GEMM weights (single bf16)
__global__ void k_convw(const float* __restrict__ We1, const float* __restrict__ We2,
                        unsigned short* __restrict__ W1b, unsigned short* __restrict__ W2b) {
    int i = blockIdx.x * 256 + threadIdx.x;
    if (i < 128 * 64) {
        int r = i >> 6, k = i & 63;
        W1b[i] = f2b(We1[(size_t)r * 192 + 64 + k]);
    } else if (i < 128 * 64 + 256 * 128) {
        int j = i - 128 * 64;
        int r = j >> 7, k = j & 127;
        W2b[j] = f2b(We2[(size_t)r * 384 + 128 + k]);
    }
}

// node-proj weights, split hi/lo bf16.
__global__ void k_convsplit(const float* __restrict__ Wn1, const float* __restrict__ We1,
                            const float* __restrict__ Wn2, const float* __restrict__ We2,
                            unsigned short* __restrict__ W1h, unsigned short* __restrict__ W1l,
                            unsigned short* __restrict__ W2h, unsigned short* __restrict__ W2l) {
    int i = blockIdx.x * 256 + threadIdx.x;
    if (i < 384 * 64) {
        int r = i >> 6, k = i & 63;
        float v;
        if (r < 128)      v = Wn1[(size_t)r * 64 + k];
        else if (r < 256) v = We1[(size_t)(r - 128) * 192 + k];
        else              v = We1[(size_t)(r - 256) * 192 + 128 + k];
        unsigned short h = f2b(v);
        W1h[i] = h; W1l[i] = f2b(v - b2f(h));
    } else if (i < 384 * 64 + 768 * 128) {
        int j = i - 384 * 64;
        int r = j >> 7, k = j & 127;
        float v;
        if (r < 256)      v = Wn2[(size_t)r * 128 + k];
        else if (r < 512) v = We2[(size_t)(r - 256) * 384 + k];
        else              v = We2[(size_t)(r - 512) * 384 + 256 + k];
        unsigned short h = f2b(v);
        W2h[j] = h; W2l[j] = f2b(v - b2f(h));
    }
}

// ---------------- fused: permute edges + convert ef to bf16 + per-node sum ----------------
__global__ void k_permagg(const float* __restrict__ ef, const int* __restrict__ eid,
                          const int* __restrict__ src, const int* __restrict__ dst,
                          const int* __restrict__ off,
                          unsigned short* __restrict__ efb_p, int* __restrict__ src_p,
                          int* __restrict__ dst_p,
                          unsigned short* __restrict__ hn1h, unsigned short* __restrict__ hn1l) {
    int bid = xcd_swz(blockIdx.x, gridDim.x);
    int w = bid * 4 + (threadIdx.x >> 6);
    int lane = threadIdx.x & 63;
    if (w >= NN) return;
    int s0 = off[w], s1 = off[w + 1];
    float acc = 0.f;
    int i = s0;
    for (; i + 4 <= s1; i += 4) {
        int e0 = eid[i], e1 = eid[i + 1], e2 = eid[i + 2], e3 = eid[i + 3];
        float v0 = ef[(size_t)e0 * 64 + lane];
        float v1 = ef[(size_t)e1 * 64 + lane];
        float v2 = ef[(size_t)e2 * 64 + lane];
        float v3 = ef[(size_t)e3 * 64 + lane];
        if (lane == 0) {
            src_p[i] = src[e0]; dst_p[i] = dst[e0];
            src_p[i + 1] = src[e1]; dst_p[i + 1] = dst[e1];
            src_p[i + 2] = src[e2]; dst_p[i + 2] = dst[e2];
            src_p[i + 3] = src[e3]; dst_p[i + 3] = dst[e3];
        }
        efb_p[(size_t)i * 64 + lane] = f2b(v0);
        efb_p[(size_t)(i + 1) * 64 + lane] = f2b(v1);
        efb_p[(size_t)(i + 2) * 64 + lane] = f2b(v2);
        efb_p[(size_t)(i + 3) * 64 + lane] = f2b(v3);
        acc += v0; acc += v1; acc += v2; acc += v3;
    }
    for (; i < s1; ++i) {
        int e = eid[i];
        float v = ef[(size_t)e * 64 + lane];
        if (lane == 0) { src_p[i] = src[e]; dst_p[i] = dst[e]; }
        efb_p[(size_t)i * 64 + lane] = f2b(v);
        acc += v;
    }
    unsigned short h = f2b(acc);
    hn1h[(size_t)w * 64 + lane] = h;
    hn1l[(size_t)w * 64 + lane] = f2b(acc - b2f(h));
}

// ---------------- fp16 table store helpers ----------------
static __device__ __forceinline__ void store_p1(unsigned short* hp1, unsigned short* pa1,
                                                unsigned short* pc1, int n, int o, float v) {
    unsigned short h = f2h(v);
    if (o < 128) {
        hp1[(size_t)n * 128 + (o & 63) * 2 + (o >> 6)] = h;
    } else if (o < 256) {
        int x = o - 128;
        pa1[(size_t)n * 128 + ((x >> 5) * 16 + (x & 15)) * 2 + ((x >> 4) & 1)] = h;
    } else {
        int x = o - 256;
        pc1[(size_t)n * 128 + ((x >> 5) * 16 + (x & 15)) * 2 + ((x >> 4) & 1)] = h;
    }
}

static __device__ __forceinline__ void store_p2(unsigned short* hp2, unsigned short* pa2,
                                                unsigned short* pc2, int n, int o, float v) {
    unsigned short h = f2h(v);
    if (o < 256) {
        hp2[(size_t)n * 256 + (o & 63) * 4 + (o >> 6)] = h;
    } else if (o < 512) {
        int x = o - 256;
        pa2[(size_t)n * 256 + (x & 63) * 4 + (x >> 6)] = h;
    } else {
        int x = o - 512;
        pc2[(size_t)n * 256 + (x & 63) * 4 + (x >> 6)] = h;
    }
}

// ---------------- node projections layer1 (split-bf16 MFMA, no LDS) ----------------
__global__ __launch_bounds__(256) void k_nodeproj1(
        const unsigned short* __restrict__ hn1h, const unsigned short* __restrict__ hn1l,
        const unsigned short* __restrict__ W1h, const unsigned short* __restrict__ W1l,
        const float* __restrict__ b1,
        unsigned short* __restrict__ hp1, unsigned short* __restrict__ pa1,
        unsigned short* __restrict__ pc1) {
    int tid = threadIdx.x;
    int w = tid >> 6, l = tid & 63;
    int c = l & 15, g = l >> 4;
    int pb = blockIdx.x * 16;

    f32x4 acc[6];
#pragma unroll
    for (int t = 0; t < 6; ++t) acc[t] = (f32x4)(0.f);

#pragma unroll
    for (int kk = 0; kk < 2; ++kk) {
        int arow = pb + c;
        bf16x8 ah = *(const bf16x8*)&hn1h[(size_t)arow * 64 + kk * 32 + g * 8];
        bf16x8 al = *(const bf16x8*)&hn1l[(size_t)arow * 64 + kk * 32 + g * 8];
#pragma unroll
        for (int t = 0; t < 6; ++t) {
            int brow = w * 96 + t * 16 + c;
            bf16x8 bh = *(const bf16x8*)&W1h[(size_t)brow * 64 + kk * 32 + g * 8];
            bf16x8 bl = *(const bf16x8*)&W1l[(size_t)brow * 64 + kk * 32 + g * 8];
            acc[t] = __builtin_amdgcn_mfma_f32_16x16x32_bf16(ah, bh, acc[t], 0, 0, 0);
            acc[t] = __builtin_amdgcn_mfma_f32_16x16x32_bf16(ah, bl, acc[t], 0, 0, 0);
            acc[t] = __builtin_amdgcn_mfma_f32_16x16x32_bf16(al, bh, acc[t], 0, 0, 0);
        }
    }

#pragma unroll
    for (int t = 0; t < 6; ++t) {
        int og = w * 96 + t * 16 + c;
        float bias = (og < 128) ? b1[og] : 0.f;
#pragma unroll
        for (int r = 0; r < 4; ++r) {
            int n = pb + g * 4 + r;
            if (n < NN) store_p1(hp1, pa1, pc1, n, og, acc[t][r] + bias);
        }
    }
}

// ---------------- edge GEMM layer1 (MFMA bf16, 64 edges/block, batched fp16 gathers) ----------------
__global__ __launch_bounds__(256) void k_gemm1(
        const unsigned short* __restrict__ efb_p, const int* __restrict__ src_p,
        const int* __restrict__ dst_p, const unsigned short* __restrict__ W1b,
        const float* __restrict__ Wa1, const unsigned short* __restrict__ pa1,
        const unsigned short* __restrict__ pc1,
        unsigned short* __restrict__ he1b, float* __restrict__ a1) {
    int tid = threadIdx.x;
    int w = tid >> 6, l = tid & 63;
    int c = l & 15, g = l >> 4;
    int pb = blockIdx.x * 64;

    f32x4 acc[4][2];
    for (int m = 0; m < 4; ++m)
        for (int t = 0; t < 2; ++t) acc[m][t] = (f32x4)(0.f);

#pragma unroll
    for (int kk = 0; kk < 2; ++kk) {
        bf16x8 b[2];
#pragma unroll
        for (int t = 0; t < 2; ++t)
            b[t] = *(const bf16x8*)&W1b[(size_t)((2 * w + t) * 16 + c) * 64 + kk * 32 + g * 8];
#pragma unroll
        for (int m = 0; m < 4; ++m) {
            bf16x8 a = *(const bf16x8*)&efb_p[(size_t)(pb + m * 16 + c) * 64 + kk * 32 + g * 8];
#pragma unroll
            for (int t = 0; t < 2; ++t)
                acc[m][t] = __builtin_amdgcn_mfma_f32_16x16x32_bf16(a, b[t], acc[m][t], 0, 0, 0);
        }
    }

    float wsj0 = Wa1[c] + Wa1[32 + c] + Wa1[64 + c] + Wa1[96 + c];
    float wsj1 = Wa1[16 + c] + Wa1[48 + c] + Wa1[80 + c] + Wa1[112 + c];
    const unsigned* paH = (const unsigned*)pa1;
    const unsigned* pcH = (const unsigned*)pc1;

    int ss[16], dd[16];
#pragma unroll
    for (int m = 0; m < 4; ++m) {
        int4 s4 = *(const int4*)&src_p[pb + m * 16 + g * 4];
        int4 d4 = *(const int4*)&dst_p[pb + m * 16 + g * 4];
        ss[m * 4 + 0] = s4.x; ss[m * 4 + 1] = s4.y; ss[m * 4 + 2] = s4.z; ss[m * 4 + 3] = s4.w;
        dd[m * 4 + 0] = d4.x; dd[m * 4 + 1] = d4.y; dd[m * 4 + 2] = d4.z; dd[m * 4 + 3] = d4.w;
    }

#pragma unroll
    for (int m = 0; m < 4; ++m) {
        unsigned ua[4], uc[4];
#pragma unroll
        for (int r = 0; r < 4; ++r) {
            ua[r] = paH[(size_t)ss[m * 4 + r] * 64 + w * 16 + c];
            uc[r] = pcH[(size_t)dd[m * 4 + r] * 64 + w * 16 + c];
        }
#pragma unroll
        for (int r = 0; r < 4; ++r) {
            int pos = pb + m * 16 + g * 4 + r;
            float2 av2 = uph2(ua[r]);
            float2 cv2 = uph2(uc[r]);
            float f0 = acc[m][0][r] + av2.x + cv2.x;
            float f1 = acc[m][1][r] + av2.y + cv2.y;
            float lf0 = (f0 > 0.f) ? f0 : 0.01f * f0;
            float lf1 = (f1 > 0.f) ? f1 : 0.01f * f1;
            float av = lf0 * wsj0 + lf1 * wsj1;
            he1b[(size_t)pos * 128 + w * 32 + c]      = f2b((lf0 > 0.f) ? lf0 : expm1f(lf0));
            he1b[(size_t)pos * 128 + w * 32 + 16 + c] = f2b((lf1 > 0.f) ? lf1 : expm1f(lf1));
            av = rowsum16(av);
            if (c == 15) a1[(size_t)pos * 4 + w] = av;
        }
    }
}

// ---------------- segment softmax + weighted aggregate, layer1 -> hi/lo bf16 ----------------
__global__ void k_agg1(const float* __restrict__ a1, const int* __restrict__ off,
                       const int* __restrict__ src_p, const unsigned short* __restrict__ hp1,
                       unsigned short* __restrict__ hn1oh, unsigned short* __restrict__ hn1ol) {
    __shared__ float4 alf[4][64];
    int wv = threadIdx.x >> 6;
    int w = xcd_swz(blockIdx.x, gridDim.x) * 4 + wv;
    int lane = threadIdx.x & 63;
    if (w >= NN) return;
    int s0 = off[w], s1 = off[w + 1];
    if (s1 == s0) {
        hn1oh[(size_t)w * 128 + lane] = 0; hn1oh[(size_t)w * 128 + 64 + lane] = 0;
        hn1ol[(size_t)w * 128 + lane] = 0; hn1ol[(size_t)w * 128 + 64 + lane] = 0;
        return;
    }
    float m[4] = {-INFINITY, -INFINITY, -INFINITY, -INFINITY};
    for (int i = s0 + lane; i < s1; i += 64) {
        float4 av = *(const float4*)&a1[(size_t)i * 4];
        m[0] = fmaxf(m[0], av.x); m[1] = fmaxf(m[1], av.y);
        m[2] = fmaxf(m[2], av.z); m[3] = fmaxf(m[3], av.w);
    }
#pragma unroll
    for (int d = 1; d < 64; d <<= 1) {
        m[0] = fmaxf(m[0], __shfl_xor(m[0], d, 64));
        m[1] = fmaxf(m[1], __shfl_xor(m[1], d, 64));
        m[2] = fmaxf(m[2], __shfl_xor(m[2], d, 64));
        m[3] = fmaxf(m[3], __shfl_xor(m[3], d, 64));
    }
    float den[4] = {0.f, 0.f, 0.f, 0.f};
    for (int i = s0 + lane; i < s1; i += 64) {
        float4 av = *(const float4*)&a1[(size_t)i * 4];
        den[0] += expf(av.x - m[0]); den[1] += expf(av.y - m[1]);
        den[2] += expf(av.z - m[2]); den[3] += expf(av.w - m[3]);
    }
#pragma unroll
    for (int d = 1; d < 64; d <<= 1) {
        den[0] += __shfl_xor(den[0], d, 64);
        den[1] += __shfl_xor(den[1], d, 64);
        den[2] += __shfl_xor(den[2], d, 64);
        den[3] += __shfl_xor(den[3], d, 64);
    }
    float r0 = 1.f / den[0], r1 = 1.f / den[1], r2 = 1.f / den[2], r3 = 1.f / den[3];
    int h0 = lane >> 5;
    const unsigned* hpH = (const unsigned*)hp1;
    float acc0 = 0.f, acc1 = 0.f;
    for (int base = s0; base < s1; base += 64) {
        int i = base + lane;
        if (i < s1) {
            float4 av = *(const float4*)&a1[(size_t)i * 4];
            float4 al;
            al.x = expf(av.x - m[0]) * r0;
            al.y = expf(av.y - m[1]) * r1;
            al.z = expf(av.z - m[2]) * r2;
            al.w = expf(av.w - m[3]) * r3;
            alf[wv][lane] = al;
        }
        int lim = s1 - base; if (lim > 64) lim = 64;
        int k = 0;
        for (; k + 8 <= lim; k += 8) {
            int sx[8];
            unsigned ux[8];
#pragma unroll
            for (int q = 0; q < 8; ++q) sx[q] = src_p[base + k + q];
#pragma unroll
            for (int q = 0; q < 8; ++q) ux[q] = hpH[(size_t)sx[q] * 64 + lane];
#pragma unroll
            for (int q = 0; q < 8; ++q) {
                float4 aq = alf[wv][k + q];
                float2 u = uph2(ux[q]);
                float w0 = (h0 == 0) ? aq.x : aq.y;
                float w1 = (h0 == 0) ? aq.z : aq.w;
                acc0 += w0 * u.x;
                acc1 += w1 * u.y;
            }
        }
        for (; k < lim; ++k) {
            float4 al = alf[wv][k];
            int s = src_p[base + k];
            float2 u = uph2(hpH[(size_t)s * 64 + lane]);
            float w0 = (h0 == 0) ? al.x : al.y;
            float w1 = (h0 == 0) ? al.z : al.w;
            acc0 += w0 * u.x;
            acc1 += w1 * u.y;
        }
    }
    float e0 = (acc0 > 0.f) ? acc0 : expm1f(acc0);
    float e1 = (acc1 > 0.f) ? acc1 : expm1f(acc1);
    unsigned short h0s = f2b(e0), h1s = f2b(e1);
    hn1oh[(size_t)w * 128 + lane] = h0s;
    hn1ol[(size_t)w * 128 + lane] = f2b(e0 - b2f(h0s));
    hn1oh[(size_t)w * 128 + 64 + lane] = h1s;
    hn1ol[(size_t)w * 128 + 64 + lane] = f2b(e1 - b2f(h1s));
}

// ---------------- node projections layer2 (split-bf16 MFMA, no LDS) ----------------
__global__ __launch_bounds__(256) void k_nodeproj2(
        const unsigned short* __restrict__ hn1oh, const unsigned short* __restrict__ hn1ol,
        const unsigned short* __restrict__ W2h, const unsigned short* __restrict__ W2l,
        const float* __restrict__ b2,
        unsigned short* __restrict__ hp2, unsigned short* __restrict__ pa2,
        unsigned short* __restrict__ pc2) {
    int tid = threadIdx.x;
    int w = tid >> 6, l = tid & 63;
    int c = l & 15, g = l >> 4;
    int pb = blockIdx.x * 16;

    f32x4 acc[12];
#pragma unroll
    for (int t = 0; t < 12; ++t) acc[t] = (f32x4)(0.f);

#pragma unroll
    for (int kk = 0; kk < 4; ++kk) {
        int arow = pb + c;
        bf16x8 ah = *(const bf16x8*)&hn1oh[(size_t)arow * 128 + kk * 32 + g * 8];
        bf16x8 al = *(const bf16x8*)&hn1ol[(size_t)arow * 128 + kk * 32 + g * 8];
#pragma unroll
        for (int t = 0; t < 12; ++t) {
            int brow = w * 192 + t * 16 + c;
            bf16x8 bh = *(const bf16x8*)&W2h[(size_t)brow * 128 + kk * 32 + g * 8];
            bf16x8 bl = *(const bf16x8*)&W2l[(size_t)brow * 128 + kk * 32 + g * 8];
            acc[t] = __builtin_amdgcn_mfma_f32_16x16x32_bf16(ah, bh, acc[t], 0, 0, 0);
            acc[t] = __builtin_amdgcn_mfma_f32_16x16x32_bf16(ah, bl, acc[t], 0, 0, 0);
            acc[t] = __builtin_amdgcn_mfma_f32_16x16x32_bf16(al, bh, acc[t], 0, 0, 0);
        }
    }

#pragma unroll
    for (int t = 0; t < 12; ++t) {
        int og = w * 192 + t * 16 + c;
        float bias = (og < 256) ? b2[og] : 0.f;
#pragma unroll
        for (int r = 0; r < 4; ++r) {
            int n = pb + g * 4 + r;
            if (n < NN) store_p2(hp2, pa2, pc2, n, og, acc[t][r] + bias);
        }
    }
}

// ---------------- edge GEMM layer2 (MFMA bf16, 64 edges/block, batched fp16 gathers) ----------------
__global__ __launch_bounds__(256) void k_gemm2(
        const unsigned short* __restrict__ he1b, const int* __restrict__ src_p,
        const int* __restrict__ dst_p, const int* __restrict__ eid,
        const unsigned short* __restrict__ W2b, const float* __restrict__ Wa2,
        const unsigned short* __restrict__ pa2, const unsigned short* __restrict__ pc2,
        float* __restrict__ heo, float* __restrict__ a2) {
    __shared__ float a2l[4 * 64 * 4];
    int tid = threadIdx.x;
    int w = tid >> 6, l = tid & 63;
    int c = l & 15, g = l >> 4;
    int j = w * 16 + c;
    int pb = blockIdx.x * 64;

    f32x4 acc[4][4];
    for (int m = 0; m < 4; ++m)
        for (int t = 0; t < 4; ++t) acc[m][t] = (f32x4)(0.f);

#pragma unroll
    for (int kk = 0; kk < 4; ++kk) {
        bf16x8 b[4];
#pragma unroll
        for (int t = 0; t < 4; ++t)
            b[t] = *(const bf16x8*)&W2b[(size_t)((w + 4 * t) * 16 + c) * 128 + kk * 32 + g * 8];
#pragma unroll
        for (int m = 0; m < 4; ++m) {
            bf16x8 a = *(const bf16x8*)&he1b[(size_t)(pb + m * 16 + c) * 128 + kk * 32 + g * 8];
#pragma unroll
            for (int t = 0; t < 4; ++t)
                acc[m][t] = __builtin_amdgcn_mfma_f32_16x16x32_bf16(a, b[t], acc[m][t], 0, 0, 0);
        }
    }

    float wsj = Wa2[j] + Wa2[64 + j] + Wa2[128 + j] + Wa2[192 + j];
    const uint2* paH = (const uint2*)pa2;
    const uint2* pcH = (const uint2*)pc2;

    int ss[16], dd[16];
#pragma unroll
    for (int m = 0; m < 4; ++m) {
        int4 s4 = *(const int4*)&src_p[pb + m * 16 + g * 4];
        int4 d4 = *(const int4*)&dst_p[pb + m * 16 + g * 4];
        ss[m * 4 + 0] = s4.x; ss[m * 4 + 1] = s4.y; ss[m * 4 + 2] = s4.z; ss[m * 4 + 3] = s4.w;
        dd[m * 4 + 0] = d4.x; dd[m * 4 + 1] = d4.y; dd[m * 4 + 2] = d4.z; dd[m * 4 + 3] = d4.w;
    }

#pragma unroll
    for (int m = 0; m < 4; ++m) {
        uint2 ua[4], uc[4];
#pragma unroll
        for (int r = 0; r < 4; ++r) {
            ua[r] = paH[(size_t)ss[m * 4 + r] * 64 + j];
            uc[r] = pcH[(size_t)dd[m * 4 + r] * 64 + j];
        }
        int4 e4 = *(const int4*)&eid[pb + m * 16 + g * 4];
        int ee[4] = {e4.x, e4.y, e4.z, e4.w};
#pragma unroll
        for (int r = 0; r < 4; ++r) {
            int le = m * 16 + g * 4 + r;
            float2 a01 = uph2(ua[r].x), a23 = uph2(ua[r].y);
            float2 c01 = uph2(uc[r].x), c23 = uph2(uc[r].y);
            float f[4];
            f[0] = acc[m][0][r] + a01.x + c01.x;
            f[1] = acc[m][1][r] + a01.y + c01.y;
            f[2] = acc[m][2][r] + a23.x + c23.x;
            f[3] = acc[m][3][r] + a23.y + c23.y;
            float hsum = 0.f;
            float avt[4];
#pragma unroll
            for (int t = 0; t < 4; ++t) {
                float lf = (f[t] > 0.f) ? f[t] : 0.01f * f[t];
                hsum += lf;
                avt[t] = lf * wsj;
            }
#pragma unroll
            for (int t = 0; t < 4; ++t) avt[t] = rowsum16(avt[t]);
            if (c == 15) {
                float4 st = make_float4(avt[0], avt[1], avt[2], avt[3]);
                *(float4*)&a2l[(w * 64 + le) * 4] = st;
            }
            heo[(size_t)ee[r] * 64 + j] = 0.25f * hsum;
        }
    }
    __syncthreads();
    {
        int pos = tid >> 2, t = tid & 3;
        float v = a2l[(0 * 64 + pos) * 4 + t] + a2l[(1 * 64 + pos) * 4 + t]
                + a2l[(2 * 64 + pos) * 4 + t] + a2l[(3 * 64 + pos) * 4 + t];
        a2[(size_t)(pb + pos) * 4 + t] = v;
    }
}

// ---------------- segment softmax + aggregate + head-mean, layer2 ----------------
__global__ void k_agg2(const float* __restrict__ a2, const int* __restrict__ off,
                       const int* __restrict__ src_p, const unsigned short* __restrict__ hp2,
                       float* __restrict__ hno) {
    __shared__ float4 alf[4][64];
    int wv = threadIdx.x >> 6;
    int w = xcd_swz(blockIdx.x, gridDim.x) * 4 + wv;
    int lane = threadIdx.x & 63;
    if (w >= NN) return;
    int s0 = off[w], s1 = off[w + 1];
    if (s1 == s0) {
        hno[(size_t)w * 64 + lane] = 0.f;
        return;
    }
    float m[4] = {-INFINITY, -INFINITY, -INFINITY, -INFINITY};
    for (int i = s0 + lane; i < s1; i += 64) {
        float4 av = *(const float4*)&a2[(size_t)i * 4];
        m[0] = fmaxf(m[0], av.x); m[1] = fmaxf(m[1], av.y);
        m[2] = fmaxf(m[2], av.z); m[3] = fmaxf(m[3], av.w);
    }
#pragma unroll
    for (int d = 1; d < 64; d <<= 1) {
        m[0] = fmaxf(m[0], __shfl_xor(m[0], d, 64));
        m[1] = fmaxf(m[1], __shfl_xor(m[1], d, 64));
        m[2] = fmaxf(m[2], __shfl_xor(m[2], d, 64));
        m[3] = fmaxf(m[3], __shfl_xor(m[3], d, 64));
    }
    float den[4] = {0.f, 0.f, 0.f, 0.f};
    for (int i = s0 + lane; i < s1; i += 64) {
        float4 av = *(const float4*)&a2[(size_t)i * 4];
        den[0] += expf(av.x - m[0]); den[1] += expf(av.y - m[1]);
        den[2] += expf(av.z - m[2]); den[3] += expf(av.w - m[3]);
    }
#pragma unroll
    for (int d = 1; d < 64; d <<= 1) {
        den[0] += __shfl_xor(den[0], d, 64);
        den[1] += __shfl_xor(den[1], d, 64);
        den[2] += __shfl_xor(den[2], d, 64);
        den[3] += __shfl_xor(den[3], d, 64);
    }
    float r0 = 1.f / den[0], r1 = 1.f / den[1], r2 = 1.f / den[2], r3 = 1.f / den[3];
    const uint2* hpH = (const uint2*)hp2;
    float acc0 = 0.f, acc1 = 0.f, acc2 = 0.f, acc3 = 0.f;
    for (int base = s0; base < s1; base += 64) {
        int i = base + lane;
        if (i < s1) {
            float4 av = *(const float4*)&a2[(size_t)i * 4];
            float4 al;
            al.x = expf(av.x - m[0]) * r0;
            al.y = expf(av.y - m[1]) * r1;
            al.z = expf(av.z - m[2]) * r2;
            al.w = expf(av.w - m[3]) * r3;
            alf[wv][lane] = al;
        }
        int lim = s1 - base; if (lim > 64) lim = 64;
        int k = 0;
        for (; k + 8 <= lim; k += 8) {
            int sx[8];
            uint2 ux[8];
#pragma unroll
            for (int q = 0; q < 8; ++q) sx[q] = src_p[base + k + q];
#pragma unroll
            for (int q = 0; q < 8; ++q) ux[q] = hpH[(size_t)sx[q] * 64 + lane];
#pragma unroll
            for (int q = 0; q < 8; ++q) {
                float4 aq = alf[wv][k + q];
                float2 u01 = uph2(ux[q].x), u23 = uph2(ux[q].y);
                acc0 += aq.x * u01.x;
                acc1 += aq.y * u01.y;
                acc2 += aq.z * u23.x;
                acc3 += aq.w * u23.y;
            }
        }
        for (; k < lim; ++k) {
            float4 al = alf[wv][k];
            int s = src_p[base + k];
            uint2 u = hpH[(size_t)s * 64 + lane];
            float2 u01 = uph2(u.x), u23 = uph2(u.y);
            acc0 += al.x * u01.x;
            acc1 += al.y * u01.y;
            acc2 += al.z * u23.x;
            acc3 += al.w * u23.y;
        }
    }
    hno[(size_t)w * 64 + lane] = 0.25f * (acc0 + acc1 + acc2 + acc3);
}

extern "C" void kernel_launch(void* const* d_in, const int* in_sizes, int n_in,
                              void* d_out, int out_size, void* d_ws, size_t ws_size,
                              hipStream_t stream) {
    const float* efeats = (const float*)d_in[1];
    const int* src = (const int*)d_in[2];
    const int* dst = (const int*)d_in[3];
    const float* Wn1 = (const float*)d_in[4];
    const float* b1  = (const float*)d_in[5];
    const float* We1 = (const float*)d_in[6];
    const float* Wa1 = (const float*)d_in[7];
    const float* Wn2 = (const float*)d_in[8];
    const float* b2  = (const float*)d_in[9];
    const float* We2 = (const float*)d_in[10];
    const float* Wa2 = (const float*)d_in[11];

    const int NNP = 30016;

    char* ws = (char*)d_ws;
    size_t o = 0;
    auto alloc = [&](size_t bytes) {
        void* p = ws + o;
        o += (bytes + 255) & ~(size_t)255;
        return p;
    };
    int* cnt   = (int*)alloc((size_t)NN * 4);
    int* off   = (int*)alloc((size_t)(NN + 1) * 4);
    int* cur   = (int*)alloc((size_t)NN * 4);
    int* eid   = (int*)alloc((size_t)NE * 4);
    int* src_p = (int*)alloc((size_t)NE * 4);
    int* dst_p = (int*)alloc((size_t)NE * 4);
    int* bsum  = (int*)alloc(64 * 4);
    int* bbase = (int*)alloc(64 * 4);
    float* a1  = (float*)alloc((size_t)NE * 4 * 4);   // reused as a2
    unsigned short* efb_p = (unsigned short*)alloc((size_t)NE * 64 * 2);
    unsigned short* he1b  = (unsigned short*)alloc((size_t)NE * 128 * 2);
    unsigned short* W1b   = (unsigned short*)alloc((size_t)128 * 64 * 2);
    unsigned short* W2b   = (unsigned short*)alloc((size_t)256 * 128 * 2);
    unsigned short* W1h   = (unsigned short*)alloc((size_t)384 * 64 * 2);
    unsigned short* W1l   = (unsigned short*)alloc((size_t)384 * 64 * 2);
    unsigned short* W2h   = (unsigned short*)alloc((size_t)768 * 128 * 2);
    unsigned short* W2l   = (unsigned short*)alloc((size_t)768 * 128 * 2);
    unsigned short* hn1h  = (unsigned short*)alloc((size_t)NNP * 64 * 2);
    unsigned short* hn1l  = (unsigned short*)alloc((size_t)NNP * 64 * 2);
    unsigned short* hn1oh = (unsigned short*)alloc((size_t)NNP * 128 * 2);
    unsigned short* hn1ol = (unsigned short*)alloc((size_t)NNP * 128 * 2);
    unsigned short* hp1   = (unsigned short*)alloc((size_t)NN * 128 * 2);
    unsigned short* pa1   = (unsigned short*)alloc((size_t)NN * 128 * 2);
    unsigned short* pc1   = (unsigned short*)alloc((size_t)NN * 128 * 2);
    unsigned short* hp2   = (unsigned short*)alloc((size_t)NN * 256 * 2);
    unsigned short* pa2   = (unsigned short*)alloc((size_t)NN * 256 * 2);
    unsigned short* pc2   = (unsigned short*)alloc((size_t)NN * 256 * 2);

    float* hno = (float*)d_out;
    float* heo = (float*)d_out + (size_t)NN * 64;

    const int SCAN_B = (NN + 1023) / 1024;
    const int NPB = NNP / 16;
    hipMemsetAsync(cnt, 0, (size_t)NN * 4, stream);
    k_count<<<(NE + 255) / 256, 256, 0, stream>>>(dst, cnt);
    k_scanA<<<SCAN_B, 1024, 0, stream>>>(cnt, off, bsum);
    k_scanB<<<1, 64, 0, stream>>>(bsum, bbase, SCAN_B);
    k_scanC<<<SCAN_B, 1024, 0, stream>>>(off, cur, bbase);
    k_fill<<<(NE + 255) / 256, 256, 0, stream>>>(dst, cur, eid);
    k_convw<<<(128 * 64 + 256 * 128 + 255) / 256, 256, 0, stream>>>(We1, We2, W1b, W2b);
    k_convsplit<<<(384 * 64 + 768 * 128 + 255) / 256, 256, 0, stream>>>(
        Wn1, We1, Wn2, We2, W1h, W1l, W2h, W2l);
    k_permagg<<<NN / 4, 256, 0, stream>>>(efeats, eid, src, dst, off, efb_p, src_p, dst_p,
                                          hn1h, hn1l);
    k_nodeproj1<<<NPB, 256, 0, stream>>>(hn1h, hn1l, W1h, W1l, b1, hp1, pa1, pc1);
    k_gemm1<<<NE / 64, 256, 0, stream>>>(efb_p, src_p, dst_p, W1b, Wa1, pa1, pc1, he1b, a1);
    k_agg1<<<NN / 4, 256, 0, stream>>>(a1, off, src_p, hp1, hn1oh, hn1ol);
    k_nodeproj2<<<NPB, 256, 0, stream>>>(hn1oh, hn1ol, W2h, W2l, b2, hp2, pa2, pc2);
    k_gemm2<<<NE / 64, 256, 0, stream>>>(he1b, src_p, dst_p, eid, W2b, Wa2, pa2, pc2, heo, a1);
    k_agg2<<<NN / 4, 256, 0, stream>>>(a1, off, src_p, hp2, hno);
}